// Round 2
// baseline (154.665 us; speedup 1.0000x reference)
//
#include <hip/hip_runtime.h>
#include <math.h>

#define B_BATCH 2048
#define N_PTS   2048
#define CHUNK   512                 // points per staged chunk
#define NCHUNK  (N_PTS / CHUNK)     // 4
#define CF4     (CHUNK * 3 / 4)     // 384 float4 of coords per chunk
#define WF4     (CHUNK / 4)         // 128 float4 of weights per chunk

// ---------------- Kernel 1: per-batch 16-way weighted reduction ----------------
// acc layout: [0]=sum w, [1..3]=sum w*s, [4..6]=sum w*t, [7+3i+j]=sum w*t_i*s_j
// Coalesced float4 global->LDS staging, then stride-3 LDS reads (conflict-free:
// gcd(3,32)=1 -> 2 lanes/bank per wave64, which is free on CDNA4).
__global__ __launch_bounds__(256) void reduce_kernel(
    const float* __restrict__ src, const float* __restrict__ tgt,
    const float* __restrict__ wts, float* __restrict__ sums)
{
    const int b   = blockIdx.x;
    const int tid = threadIdx.x;

    const float4* s4 = (const float4*)(src + (size_t)b * N_PTS * 3);
    const float4* t4 = (const float4*)(tgt + (size_t)b * N_PTS * 3);
    const float4* w4 = (const float4*)(wts + (size_t)b * N_PTS);

    __shared__ float s_s[CHUNK * 3];
    __shared__ float s_t[CHUNK * 3];
    __shared__ float s_w[CHUNK];

    float acc[16];
#pragma unroll
    for (int i = 0; i < 16; ++i) acc[i] = 0.f;

    for (int c = 0; c < NCHUNK; ++c) {
        // ---- stage (fully coalesced dwordx4) ----
        float4* ds = (float4*)s_s;
        float4* dt = (float4*)s_t;
        float4* dw = (float4*)s_w;
        const int cbase = c * CF4;
        // CF4 = 384 = 256 + 128
        ds[tid] = s4[cbase + tid];
        dt[tid] = t4[cbase + tid];
        if (tid < CF4 - 256) {
            ds[256 + tid] = s4[cbase + 256 + tid];
            dt[256 + tid] = t4[cbase + 256 + tid];
        }
        if (tid < WF4) dw[tid] = w4[c * WF4 + tid];
        __syncthreads();

        // ---- accumulate: 2 points per thread ----
#pragma unroll
        for (int k = 0; k < CHUNK / 256; ++k) {
            const int p = tid + k * 256;
            const float w  = s_w[p];
            const float sx = s_s[3*p+0], sy = s_s[3*p+1], sz = s_s[3*p+2];
            const float tx = s_t[3*p+0], ty = s_t[3*p+1], tz = s_t[3*p+2];
            const float wsx = w * sx, wsy = w * sy, wsz = w * sz;
            acc[0]  += w;
            acc[1]  += wsx;      acc[2]  += wsy;      acc[3]  += wsz;
            acc[4]  += w * tx;   acc[5]  += w * ty;   acc[6]  += w * tz;
            acc[7]  += tx * wsx; acc[8]  += tx * wsy; acc[9]  += tx * wsz;
            acc[10] += ty * wsx; acc[11] += ty * wsy; acc[12] += ty * wsz;
            acc[13] += tz * wsx; acc[14] += tz * wsy; acc[15] += tz * wsz;
        }
        __syncthreads();
    }

    // wave-level reduce (wave64)
#pragma unroll
    for (int i = 0; i < 16; ++i) {
#pragma unroll
        for (int off = 32; off > 0; off >>= 1)
            acc[i] += __shfl_down(acc[i], off, 64);
    }

    __shared__ float red[4][16];
    const int lane = tid & 63, wv = tid >> 6;
    if (lane == 0) {
#pragma unroll
        for (int i = 0; i < 16; ++i) red[wv][i] = acc[i];
    }
    __syncthreads();
    if (tid < 16)
        sums[(size_t)b * 16 + tid] =
            red[0][tid] + red[1][tid] + red[2][tid] + red[3][tid];
}

// ---------------- Kernel 2: per-batch 3x3 SVD + Kabsch assembly ----------------
__global__ __launch_bounds__(256) void svd_kernel(
    const float* __restrict__ sums,
    float* __restrict__ outR, float* __restrict__ outT)
{
    const int b = blockIdx.x * blockDim.x + threadIdx.x;
    if (b >= B_BATCH) return;
    const float* S = sums + (size_t)b * 16;

    const double wtot = (double)S[0] + 1e-4;
    const double inv  = 1.0 / wtot;
    double sc[3] = { S[1]*inv, S[2]*inv, S[3]*inv };
    double tc[3] = { S[4]*inv, S[5]*inv, S[6]*inv };
    const double f = (wtot + 1e-4) * inv;   // exact centering correction

    double W[3][3];
#pragma unroll
    for (int i = 0; i < 3; ++i)
#pragma unroll
        for (int j = 0; j < 3; ++j)
            W[i][j] = (double)S[7 + 3*i + j] * inv - f * tc[i] * sc[j];

    // A = W^T W (symmetric)
    double A[3][3];
    for (int i = 0; i < 3; ++i)
        for (int j = 0; j < 3; ++j) {
            double s = 0.0;
            for (int k = 0; k < 3; ++k) s += W[k][i] * W[k][j];
            A[i][j] = s;
        }

    // cyclic Jacobi eigen-decomposition; quadratic convergence -> ~4 sweeps.
    // Relative early-exit (1e-28 * trace) instead of absolute 1e-300: cuts the
    // dependent fp64 div/sqrt chain ~3x on this latency-bound kernel.
    double V[3][3] = {{1,0,0},{0,1,0},{0,0,1}};
    const double tr0 = fabs(A[0][0]) + fabs(A[1][1]) + fabs(A[2][2]) + 1e-300;
    for (int sweep = 0; sweep < 8; ++sweep) {
        double offd = fabs(A[0][1]) + fabs(A[0][2]) + fabs(A[1][2]);
        if (offd <= 1e-28 * tr0) break;
        for (int pq = 0; pq < 3; ++pq) {
            const int p = (pq == 2) ? 1 : 0;
            const int q = (pq == 0) ? 1 : 2;
            const double apq = A[p][q];
            if (fabs(apq) == 0.0) continue;
            const double tau = (A[q][q] - A[p][p]) / (2.0 * apq);
            const double tt  = (tau >= 0.0 ? 1.0 : -1.0) /
                               (fabs(tau) + sqrt(1.0 + tau * tau));
            const double c = 1.0 / sqrt(1.0 + tt * tt);
            const double s = tt * c;
            for (int k = 0; k < 3; ++k) {
                const double akp = A[k][p], akq = A[k][q];
                A[k][p] = c * akp - s * akq;
                A[k][q] = s * akp + c * akq;
            }
            for (int k = 0; k < 3; ++k) {
                const double apk = A[p][k], aqk = A[q][k];
                A[p][k] = c * apk - s * aqk;
                A[q][k] = s * apk + c * aqk;
            }
            for (int k = 0; k < 3; ++k) {
                const double vkp = V[k][p], vkq = V[k][q];
                V[k][p] = c * vkp - s * vkq;
                V[k][q] = s * vkp + c * vkq;
            }
        }
    }

    // sort eigenvalues descending (numpy returns descending singular values)
    double lam[3] = { A[0][0], A[1][1], A[2][2] };
    int idx[3] = {0, 1, 2};
    if (lam[idx[0]] < lam[idx[1]]) { int t_ = idx[0]; idx[0] = idx[1]; idx[1] = t_; }
    if (lam[idx[0]] < lam[idx[2]]) { int t_ = idx[0]; idx[0] = idx[2]; idx[2] = t_; }
    if (lam[idx[1]] < lam[idx[2]]) { int t_ = idx[1]; idx[1] = idx[2]; idx[2] = t_; }

    double v[3][3]; // sorted eigenvector columns: v[r][c]
#pragma unroll
    for (int c = 0; c < 3; ++c)
        for (int r = 0; r < 3; ++r) v[r][c] = V[r][idx[c]];

    // U columns via Gram-Schmidt of W*v_c, with fallbacks for tiny sigma
    double u[3][3];
    double col[3];
    // col 0
    for (int r = 0; r < 3; ++r)
        col[r] = W[r][0]*v[0][0] + W[r][1]*v[1][0] + W[r][2]*v[2][0];
    double s0 = sqrt(col[0]*col[0] + col[1]*col[1] + col[2]*col[2]);
    if (s0 > 1e-150) {
        for (int r = 0; r < 3; ++r) u[r][0] = col[r] / s0;
    } else {
        u[0][0] = 1.0; u[1][0] = 0.0; u[2][0] = 0.0;
    }
    // col 1
    for (int r = 0; r < 3; ++r)
        col[r] = W[r][0]*v[0][1] + W[r][1]*v[1][1] + W[r][2]*v[2][1];
    {
        double d01 = col[0]*u[0][0] + col[1]*u[1][0] + col[2]*u[2][0];
        for (int r = 0; r < 3; ++r) col[r] -= d01 * u[r][0];
        double s1 = sqrt(col[0]*col[0] + col[1]*col[1] + col[2]*col[2]);
        if (s1 > 1e-12 * (1.0 + s0)) {
            for (int r = 0; r < 3; ++r) u[r][1] = col[r] / s1;
        } else {
            double ax = fabs(u[0][0]), ay = fabs(u[1][0]), az = fabs(u[2][0]);
            double e[3] = {0, 0, 0};
            if (ax <= ay && ax <= az) e[0] = 1.0;
            else if (ay <= az)        e[1] = 1.0;
            else                      e[2] = 1.0;
            double p0 = u[1][0]*e[2] - u[2][0]*e[1];
            double p1 = u[2][0]*e[0] - u[0][0]*e[2];
            double p2 = u[0][0]*e[1] - u[1][0]*e[0];
            double pn = sqrt(p0*p0 + p1*p1 + p2*p2);
            u[0][1] = p0/pn; u[1][1] = p1/pn; u[2][1] = p2/pn;
        }
    }
    // col 2
    for (int r = 0; r < 3; ++r)
        col[r] = W[r][0]*v[0][2] + W[r][1]*v[1][2] + W[r][2]*v[2][2];
    {
        double d02 = col[0]*u[0][0] + col[1]*u[1][0] + col[2]*u[2][0];
        double d12 = col[0]*u[0][1] + col[1]*u[1][1] + col[2]*u[2][1];
        for (int r = 0; r < 3; ++r) col[r] -= d02 * u[r][0] + d12 * u[r][1];
        double s2 = sqrt(col[0]*col[0] + col[1]*col[1] + col[2]*col[2]);
        if (s2 > 1e-12 * (1.0 + s0)) {
            for (int r = 0; r < 3; ++r) u[r][2] = col[r] / s2;
        } else {
            // sigma3 ~ 0: u3 = u0 x u1 (R is gauge-invariant in this case)
            u[0][2] = u[1][0]*u[2][1] - u[2][0]*u[1][1];
            u[1][2] = u[2][0]*u[0][1] - u[0][0]*u[2][1];
            u[2][2] = u[0][0]*u[1][1] - u[1][0]*u[0][1];
        }
    }

    // d = sign(det(U) * det(V))
    double detU =
        u[0][0]*(u[1][1]*u[2][2] - u[2][1]*u[1][2]) -
        u[0][1]*(u[1][0]*u[2][2] - u[2][0]*u[1][2]) +
        u[0][2]*(u[1][0]*u[2][1] - u[2][0]*u[1][1]);
    double detV =
        v[0][0]*(v[1][1]*v[2][2] - v[2][1]*v[1][2]) -
        v[0][1]*(v[1][0]*v[2][2] - v[2][0]*v[1][2]) +
        v[0][2]*(v[1][0]*v[2][1] - v[2][0]*v[1][1]);
    const double d = (detU * detV >= 0.0) ? 1.0 : -1.0;

    // R = u0 v0^T + u1 v1^T + d * u2 v2^T ; t = tc - R*sc
    double R[3][3];
#pragma unroll
    for (int r = 0; r < 3; ++r)
#pragma unroll
        for (int c = 0; c < 3; ++c)
            R[r][c] = u[r][0]*v[c][0] + u[r][1]*v[c][1] + d * u[r][2]*v[c][2];

    float* Rb = outR + (size_t)b * 9;
#pragma unroll
    for (int r = 0; r < 3; ++r)
#pragma unroll
        for (int c = 0; c < 3; ++c)
            Rb[3*r + c] = (float)R[r][c];

    float* Tb = outT + (size_t)b * 3;
#pragma unroll
    for (int r = 0; r < 3; ++r)
        Tb[r] = (float)(tc[r] - (R[r][0]*sc[0] + R[r][1]*sc[1] + R[r][2]*sc[2]));
}

extern "C" void kernel_launch(void* const* d_in, const int* in_sizes, int n_in,
                              void* d_out, int out_size, void* d_ws, size_t ws_size,
                              hipStream_t stream) {
    const float* src = (const float*)d_in[0];   // (B,N,3)
    const float* tgt = (const float*)d_in[1];   // (B,N,3)
    const float* wts = (const float*)d_in[2];   // (B,1,N)
    float* outR = (float*)d_out;                // (B,3,3) flat
    float* outT = outR + (size_t)B_BATCH * 9;   // (B,3,1) flat
    float* sums = (float*)d_ws;                 // (B,16) scratch

    reduce_kernel<<<B_BATCH, 256, 0, stream>>>(src, tgt, wts, sums);
    svd_kernel<<<(B_BATCH + 255) / 256, 256, 0, stream>>>(sums, outR, outT);
}

// Round 3
// 148.744 us; speedup vs baseline: 1.0398x; 1.0398x over previous
//
#include <hip/hip_runtime.h>
#include <math.h>

#define B_BATCH 2048
#define N_PTS   2048

// ---------------- Kernel 1: per-batch 16-way weighted reduction ----------------
// acc layout: [0]=sum w, [1..3]=sum w*s, [4..6]=sum w*t, [7+3i+j]=sum w*t_i*s_j
// One block per batch, 8 points/thread. Direct float4 loads (lane stride 96B):
// every cache line fetched exactly once; 14 independent loads in flight per
// thread, NO barriers in the streaming path -> max memory-level parallelism.
__global__ __launch_bounds__(256) void reduce_kernel(
    const float* __restrict__ src, const float* __restrict__ tgt,
    const float* __restrict__ wts, float* __restrict__ sums)
{
    const int b   = blockIdx.x;
    const int tid = threadIdx.x;

    const float4* s4 = (const float4*)(src + (size_t)b * N_PTS * 3);
    const float4* t4 = (const float4*)(tgt + (size_t)b * N_PTS * 3);
    const float4* w4 = (const float4*)(wts + (size_t)b * N_PTS);

    // thread handles points [8*tid, 8*tid+8): 6 coord float4 each + 2 weight float4
    float4 sv[6], tv[6], wv[2];
#pragma unroll
    for (int k = 0; k < 6; ++k) sv[k] = s4[6 * tid + k];
#pragma unroll
    for (int k = 0; k < 6; ++k) tv[k] = t4[6 * tid + k];
    wv[0] = w4[2 * tid];
    wv[1] = w4[2 * tid + 1];

    const float* sf = (const float*)sv;
    const float* tf = (const float*)tv;
    const float* wf = (const float*)wv;

    float acc[16];
#pragma unroll
    for (int i = 0; i < 16; ++i) acc[i] = 0.f;

#pragma unroll
    for (int p = 0; p < 8; ++p) {
        const float w  = wf[p];
        const float sx = sf[3*p+0], sy = sf[3*p+1], sz = sf[3*p+2];
        const float tx = tf[3*p+0], ty = tf[3*p+1], tz = tf[3*p+2];
        const float wsx = w * sx, wsy = w * sy, wsz = w * sz;
        acc[0]  += w;
        acc[1]  += wsx;      acc[2]  += wsy;      acc[3]  += wsz;
        acc[4]  += w * tx;   acc[5]  += w * ty;   acc[6]  += w * tz;
        acc[7]  += tx * wsx; acc[8]  += tx * wsy; acc[9]  += tx * wsz;
        acc[10] += ty * wsx; acc[11] += ty * wsy; acc[12] += ty * wsz;
        acc[13] += tz * wsx; acc[14] += tz * wsy; acc[15] += tz * wsz;
    }

    // wave-level reduce (wave64)
#pragma unroll
    for (int i = 0; i < 16; ++i) {
#pragma unroll
        for (int off = 32; off > 0; off >>= 1)
            acc[i] += __shfl_down(acc[i], off, 64);
    }

    __shared__ float red[4][16];
    const int lane = tid & 63, wv_ = tid >> 6;
    if (lane == 0) {
#pragma unroll
        for (int i = 0; i < 16; ++i) red[wv_][i] = acc[i];
    }
    __syncthreads();
    if (tid < 16)
        sums[(size_t)b * 16 + tid] =
            red[0][tid] + red[1][tid] + red[2][tid] + red[3][tid];
}

// ---------------- Kernel 2: per-batch 3x3 SVD + Kabsch assembly ----------------
// 64-thread blocks -> 32 blocks over 32 CUs (vs 8): spreads the fp64 latency chain.
__global__ __launch_bounds__(64) void svd_kernel(
    const float* __restrict__ sums,
    float* __restrict__ outR, float* __restrict__ outT)
{
    const int b = blockIdx.x * blockDim.x + threadIdx.x;
    if (b >= B_BATCH) return;
    const float* S = sums + (size_t)b * 16;

    const double wtot = (double)S[0] + 1e-4;
    const double inv  = 1.0 / wtot;
    double sc[3] = { S[1]*inv, S[2]*inv, S[3]*inv };
    double tc[3] = { S[4]*inv, S[5]*inv, S[6]*inv };
    const double f = (wtot + 1e-4) * inv;   // exact centering correction

    double W[3][3];
#pragma unroll
    for (int i = 0; i < 3; ++i)
#pragma unroll
        for (int j = 0; j < 3; ++j)
            W[i][j] = (double)S[7 + 3*i + j] * inv - f * tc[i] * sc[j];

    // A = W^T W (symmetric)
    double A[3][3];
    for (int i = 0; i < 3; ++i)
        for (int j = 0; j < 3; ++j) {
            double s = 0.0;
            for (int k = 0; k < 3; ++k) s += W[k][i] * W[k][j];
            A[i][j] = s;
        }

    // cyclic Jacobi eigen-decomposition; quadratic convergence -> ~4 sweeps.
    double V[3][3] = {{1,0,0},{0,1,0},{0,0,1}};
    const double tr0 = fabs(A[0][0]) + fabs(A[1][1]) + fabs(A[2][2]) + 1e-300;
    for (int sweep = 0; sweep < 8; ++sweep) {
        double offd = fabs(A[0][1]) + fabs(A[0][2]) + fabs(A[1][2]);
        if (offd <= 1e-28 * tr0) break;
        for (int pq = 0; pq < 3; ++pq) {
            const int p = (pq == 2) ? 1 : 0;
            const int q = (pq == 0) ? 1 : 2;
            const double apq = A[p][q];
            if (fabs(apq) == 0.0) continue;
            const double tau = (A[q][q] - A[p][p]) / (2.0 * apq);
            const double tt  = (tau >= 0.0 ? 1.0 : -1.0) /
                               (fabs(tau) + sqrt(1.0 + tau * tau));
            const double c = 1.0 / sqrt(1.0 + tt * tt);
            const double s = tt * c;
            for (int k = 0; k < 3; ++k) {
                const double akp = A[k][p], akq = A[k][q];
                A[k][p] = c * akp - s * akq;
                A[k][q] = s * akp + c * akq;
            }
            for (int k = 0; k < 3; ++k) {
                const double apk = A[p][k], aqk = A[q][k];
                A[p][k] = c * apk - s * aqk;
                A[q][k] = s * apk + c * aqk;
            }
            for (int k = 0; k < 3; ++k) {
                const double vkp = V[k][p], vkq = V[k][q];
                V[k][p] = c * vkp - s * vkq;
                V[k][q] = s * vkp + c * vkq;
            }
        }
    }

    // sort eigenvalues descending (numpy returns descending singular values)
    double lam[3] = { A[0][0], A[1][1], A[2][2] };
    int idx[3] = {0, 1, 2};
    if (lam[idx[0]] < lam[idx[1]]) { int t_ = idx[0]; idx[0] = idx[1]; idx[1] = t_; }
    if (lam[idx[0]] < lam[idx[2]]) { int t_ = idx[0]; idx[0] = idx[2]; idx[2] = t_; }
    if (lam[idx[1]] < lam[idx[2]]) { int t_ = idx[1]; idx[1] = idx[2]; idx[2] = t_; }

    double v[3][3]; // sorted eigenvector columns: v[r][c]
#pragma unroll
    for (int c = 0; c < 3; ++c)
        for (int r = 0; r < 3; ++r) v[r][c] = V[r][idx[c]];

    // U columns via Gram-Schmidt of W*v_c, with fallbacks for tiny sigma
    double u[3][3];
    double col[3];
    // col 0
    for (int r = 0; r < 3; ++r)
        col[r] = W[r][0]*v[0][0] + W[r][1]*v[1][0] + W[r][2]*v[2][0];
    double s0 = sqrt(col[0]*col[0] + col[1]*col[1] + col[2]*col[2]);
    if (s0 > 1e-150) {
        for (int r = 0; r < 3; ++r) u[r][0] = col[r] / s0;
    } else {
        u[0][0] = 1.0; u[1][0] = 0.0; u[2][0] = 0.0;
    }
    // col 1
    for (int r = 0; r < 3; ++r)
        col[r] = W[r][0]*v[0][1] + W[r][1]*v[1][1] + W[r][2]*v[2][1];
    {
        double d01 = col[0]*u[0][0] + col[1]*u[1][0] + col[2]*u[2][0];
        for (int r = 0; r < 3; ++r) col[r] -= d01 * u[r][0];
        double s1 = sqrt(col[0]*col[0] + col[1]*col[1] + col[2]*col[2]);
        if (s1 > 1e-12 * (1.0 + s0)) {
            for (int r = 0; r < 3; ++r) u[r][1] = col[r] / s1;
        } else {
            double ax = fabs(u[0][0]), ay = fabs(u[1][0]), az = fabs(u[2][0]);
            double e[3] = {0, 0, 0};
            if (ax <= ay && ax <= az) e[0] = 1.0;
            else if (ay <= az)        e[1] = 1.0;
            else                      e[2] = 1.0;
            double p0 = u[1][0]*e[2] - u[2][0]*e[1];
            double p1 = u[2][0]*e[0] - u[0][0]*e[2];
            double p2 = u[0][0]*e[1] - u[1][0]*e[0];
            double pn = sqrt(p0*p0 + p1*p1 + p2*p2);
            u[0][1] = p0/pn; u[1][1] = p1/pn; u[2][1] = p2/pn;
        }
    }
    // col 2
    for (int r = 0; r < 3; ++r)
        col[r] = W[r][0]*v[0][2] + W[r][1]*v[1][2] + W[r][2]*v[2][2];
    {
        double d02 = col[0]*u[0][0] + col[1]*u[1][0] + col[2]*u[2][0];
        double d12 = col[0]*u[0][1] + col[1]*u[1][1] + col[2]*u[2][1];
        for (int r = 0; r < 3; ++r) col[r] -= d02 * u[r][0] + d12 * u[r][1];
        double s2 = sqrt(col[0]*col[0] + col[1]*col[1] + col[2]*col[2]);
        if (s2 > 1e-12 * (1.0 + s0)) {
            for (int r = 0; r < 3; ++r) u[r][2] = col[r] / s2;
        } else {
            // sigma3 ~ 0: u3 = u0 x u1 (R is gauge-invariant in this case)
            u[0][2] = u[1][0]*u[2][1] - u[2][0]*u[1][1];
            u[1][2] = u[2][0]*u[0][1] - u[0][0]*u[2][1];
            u[2][2] = u[0][0]*u[1][1] - u[1][0]*u[0][1];
        }
    }

    // d = sign(det(U) * det(V))
    double detU =
        u[0][0]*(u[1][1]*u[2][2] - u[2][1]*u[1][2]) -
        u[0][1]*(u[1][0]*u[2][2] - u[2][0]*u[1][2]) +
        u[0][2]*(u[1][0]*u[2][1] - u[2][0]*u[1][1]);
    double detV =
        v[0][0]*(v[1][1]*v[2][2] - v[2][1]*v[1][2]) -
        v[0][1]*(v[1][0]*v[2][2] - v[2][0]*v[1][2]) +
        v[0][2]*(v[1][0]*v[2][1] - v[2][0]*v[1][1]);
    const double d = (detU * detV >= 0.0) ? 1.0 : -1.0;

    // R = u0 v0^T + u1 v1^T + d * u2 v2^T ; t = tc - R*sc
    double R[3][3];
#pragma unroll
    for (int r = 0; r < 3; ++r)
#pragma unroll
        for (int c = 0; c < 3; ++c)
            R[r][c] = u[r][0]*v[c][0] + u[r][1]*v[c][1] + d * u[r][2]*v[c][2];

    float* Rb = outR + (size_t)b * 9;
#pragma unroll
    for (int r = 0; r < 3; ++r)
#pragma unroll
        for (int c = 0; c < 3; ++c)
            Rb[3*r + c] = (float)R[r][c];

    float* Tb = outT + (size_t)b * 3;
#pragma unroll
    for (int r = 0; r < 3; ++r)
        Tb[r] = (float)(tc[r] - (R[r][0]*sc[0] + R[r][1]*sc[1] + R[r][2]*sc[2]));
}

extern "C" void kernel_launch(void* const* d_in, const int* in_sizes, int n_in,
                              void* d_out, int out_size, void* d_ws, size_t ws_size,
                              hipStream_t stream) {
    const float* src = (const float*)d_in[0];   // (B,N,3)
    const float* tgt = (const float*)d_in[1];   // (B,N,3)
    const float* wts = (const float*)d_in[2];   // (B,1,N)
    float* outR = (float*)d_out;                // (B,3,3) flat
    float* outT = outR + (size_t)B_BATCH * 9;   // (B,3,1) flat
    float* sums = (float*)d_ws;                 // (B,16) scratch

    reduce_kernel<<<B_BATCH, 256, 0, stream>>>(src, tgt, wts, sums);
    svd_kernel<<<B_BATCH / 64, 64, 0, stream>>>(sums, outR, outT);
}

// Round 4
// 142.853 us; speedup vs baseline: 1.0827x; 1.0412x over previous
//
#include <hip/hip_runtime.h>
#include <math.h>

#define B_BATCH 2048
#define N_PTS   2048

// ---------------- Kernel 1: per-batch 16-way weighted reduction ----------------
// acc layout: [0]=sum w, [1..3]=sum w*s, [4..6]=sum w*t, [7+3i+j]=sum w*t_i*s_j
// TWO blocks per batch (4096 blocks), 4 points/thread = 7 float4 loads = 28
// VGPRs of load data -> all loads in flight simultaneously (R3's VGPR_Count=40
// proved 8-pt/thread forced the compiler to serialize load rounds). Each block
// writes a 16-float partial; svd_kernel sums the two halves.
__global__ __launch_bounds__(256) void reduce_kernel(
    const float* __restrict__ src, const float* __restrict__ tgt,
    const float* __restrict__ wts, float* __restrict__ sums)
{
    const int bid  = blockIdx.x;
    const int b    = bid >> 1;
    const int half = bid & 1;
    const int tid  = threadIdx.x;

    const float4* s4 = (const float4*)(src + (size_t)b * N_PTS * 3) + half * 768;
    const float4* t4 = (const float4*)(tgt + (size_t)b * N_PTS * 3) + half * 768;
    const float4* w4 = (const float4*)(wts + (size_t)b * N_PTS) + half * 256;

    // thread handles points [4*tid, 4*tid+4) of this half: 3 coord f4 + 1 weight f4
    float4 sv[3], tv[3], wq;
#pragma unroll
    for (int k = 0; k < 3; ++k) sv[k] = s4[3 * tid + k];
#pragma unroll
    for (int k = 0; k < 3; ++k) tv[k] = t4[3 * tid + k];
    wq = w4[tid];

    const float* sf = (const float*)sv;
    const float* tf = (const float*)tv;
    const float* wf = (const float*)&wq;

    float acc[16];
#pragma unroll
    for (int i = 0; i < 16; ++i) acc[i] = 0.f;

#pragma unroll
    for (int p = 0; p < 4; ++p) {
        const float w  = wf[p];
        const float sx = sf[3*p+0], sy = sf[3*p+1], sz = sf[3*p+2];
        const float tx = tf[3*p+0], ty = tf[3*p+1], tz = tf[3*p+2];
        const float wsx = w * sx, wsy = w * sy, wsz = w * sz;
        acc[0]  += w;
        acc[1]  += wsx;      acc[2]  += wsy;      acc[3]  += wsz;
        acc[4]  += w * tx;   acc[5]  += w * ty;   acc[6]  += w * tz;
        acc[7]  += tx * wsx; acc[8]  += tx * wsy; acc[9]  += tx * wsz;
        acc[10] += ty * wsx; acc[11] += ty * wsy; acc[12] += ty * wsz;
        acc[13] += tz * wsx; acc[14] += tz * wsy; acc[15] += tz * wsz;
    }

    // wave-level reduce (wave64)
#pragma unroll
    for (int i = 0; i < 16; ++i) {
#pragma unroll
        for (int off = 32; off > 0; off >>= 1)
            acc[i] += __shfl_down(acc[i], off, 64);
    }

    __shared__ float red[4][16];
    const int lane = tid & 63, wv_ = tid >> 6;
    if (lane == 0) {
#pragma unroll
        for (int i = 0; i < 16; ++i) red[wv_][i] = acc[i];
    }
    __syncthreads();
    if (tid < 16)
        sums[(size_t)bid * 16 + tid] =
            red[0][tid] + red[1][tid] + red[2][tid] + red[3][tid];
}

// ---------------- Kernel 2: per-batch 3x3 SVD + Kabsch assembly ----------------
__global__ __launch_bounds__(64) void svd_kernel(
    const float* __restrict__ sums,
    float* __restrict__ outR, float* __restrict__ outT)
{
    const int b = blockIdx.x * blockDim.x + threadIdx.x;
    if (b >= B_BATCH) return;
    const float* P0 = sums + (size_t)b * 32;
    const float* P1 = P0 + 16;
    float S[16];
#pragma unroll
    for (int i = 0; i < 16; ++i) S[i] = P0[i] + P1[i];

    const double wtot = (double)S[0] + 1e-4;
    const double inv  = 1.0 / wtot;
    double sc[3] = { S[1]*inv, S[2]*inv, S[3]*inv };
    double tc[3] = { S[4]*inv, S[5]*inv, S[6]*inv };
    const double f = (wtot + 1e-4) * inv;   // exact centering correction

    double W[3][3];
#pragma unroll
    for (int i = 0; i < 3; ++i)
#pragma unroll
        for (int j = 0; j < 3; ++j)
            W[i][j] = (double)S[7 + 3*i + j] * inv - f * tc[i] * sc[j];

    // A = W^T W (symmetric)
    double A[3][3];
    for (int i = 0; i < 3; ++i)
        for (int j = 0; j < 3; ++j) {
            double s = 0.0;
            for (int k = 0; k < 3; ++k) s += W[k][i] * W[k][j];
            A[i][j] = s;
        }

    // cyclic Jacobi eigen-decomposition; quadratic convergence -> ~4 sweeps.
    double V[3][3] = {{1,0,0},{0,1,0},{0,0,1}};
    const double tr0 = fabs(A[0][0]) + fabs(A[1][1]) + fabs(A[2][2]) + 1e-300;
    for (int sweep = 0; sweep < 8; ++sweep) {
        double offd = fabs(A[0][1]) + fabs(A[0][2]) + fabs(A[1][2]);
        if (offd <= 1e-28 * tr0) break;
        for (int pq = 0; pq < 3; ++pq) {
            const int p = (pq == 2) ? 1 : 0;
            const int q = (pq == 0) ? 1 : 2;
            const double apq = A[p][q];
            if (fabs(apq) == 0.0) continue;
            const double tau = (A[q][q] - A[p][p]) / (2.0 * apq);
            const double tt  = (tau >= 0.0 ? 1.0 : -1.0) /
                               (fabs(tau) + sqrt(1.0 + tau * tau));
            const double c = 1.0 / sqrt(1.0 + tt * tt);
            const double s = tt * c;
            for (int k = 0; k < 3; ++k) {
                const double akp = A[k][p], akq = A[k][q];
                A[k][p] = c * akp - s * akq;
                A[k][q] = s * akp + c * akq;
            }
            for (int k = 0; k < 3; ++k) {
                const double apk = A[p][k], aqk = A[q][k];
                A[p][k] = c * apk - s * aqk;
                A[q][k] = s * apk + c * aqk;
            }
            for (int k = 0; k < 3; ++k) {
                const double vkp = V[k][p], vkq = V[k][q];
                V[k][p] = c * vkp - s * vkq;
                V[k][q] = s * vkp + c * vkq;
            }
        }
    }

    // sort eigenvalues descending (numpy returns descending singular values)
    double lam[3] = { A[0][0], A[1][1], A[2][2] };
    int idx[3] = {0, 1, 2};
    if (lam[idx[0]] < lam[idx[1]]) { int t_ = idx[0]; idx[0] = idx[1]; idx[1] = t_; }
    if (lam[idx[0]] < lam[idx[2]]) { int t_ = idx[0]; idx[0] = idx[2]; idx[2] = t_; }
    if (lam[idx[1]] < lam[idx[2]]) { int t_ = idx[1]; idx[1] = idx[2]; idx[2] = t_; }

    double v[3][3]; // sorted eigenvector columns: v[r][c]
#pragma unroll
    for (int c = 0; c < 3; ++c)
        for (int r = 0; r < 3; ++r) v[r][c] = V[r][idx[c]];

    // U columns via Gram-Schmidt of W*v_c, with fallbacks for tiny sigma
    double u[3][3];
    double col[3];
    // col 0
    for (int r = 0; r < 3; ++r)
        col[r] = W[r][0]*v[0][0] + W[r][1]*v[1][0] + W[r][2]*v[2][0];
    double s0 = sqrt(col[0]*col[0] + col[1]*col[1] + col[2]*col[2]);
    if (s0 > 1e-150) {
        for (int r = 0; r < 3; ++r) u[r][0] = col[r] / s0;
    } else {
        u[0][0] = 1.0; u[1][0] = 0.0; u[2][0] = 0.0;
    }
    // col 1
    for (int r = 0; r < 3; ++r)
        col[r] = W[r][0]*v[0][1] + W[r][1]*v[1][1] + W[r][2]*v[2][1];
    {
        double d01 = col[0]*u[0][0] + col[1]*u[1][0] + col[2]*u[2][0];
        for (int r = 0; r < 3; ++r) col[r] -= d01 * u[r][0];
        double s1 = sqrt(col[0]*col[0] + col[1]*col[1] + col[2]*col[2]);
        if (s1 > 1e-12 * (1.0 + s0)) {
            for (int r = 0; r < 3; ++r) u[r][1] = col[r] / s1;
        } else {
            double ax = fabs(u[0][0]), ay = fabs(u[1][0]), az = fabs(u[2][0]);
            double e[3] = {0, 0, 0};
            if (ax <= ay && ax <= az) e[0] = 1.0;
            else if (ay <= az)        e[1] = 1.0;
            else                      e[2] = 1.0;
            double p0 = u[1][0]*e[2] - u[2][0]*e[1];
            double p1 = u[2][0]*e[0] - u[0][0]*e[2];
            double p2 = u[0][0]*e[1] - u[1][0]*e[0];
            double pn = sqrt(p0*p0 + p1*p1 + p2*p2);
            u[0][1] = p0/pn; u[1][1] = p1/pn; u[2][1] = p2/pn;
        }
    }
    // col 2
    for (int r = 0; r < 3; ++r)
        col[r] = W[r][0]*v[0][2] + W[r][1]*v[1][2] + W[r][2]*v[2][2];
    {
        double d02 = col[0]*u[0][0] + col[1]*u[1][0] + col[2]*u[2][0];
        double d12 = col[0]*u[0][1] + col[1]*u[1][1] + col[2]*u[2][1];
        for (int r = 0; r < 3; ++r) col[r] -= d02 * u[r][0] + d12 * u[r][1];
        double s2 = sqrt(col[0]*col[0] + col[1]*col[1] + col[2]*col[2]);
        if (s2 > 1e-12 * (1.0 + s0)) {
            for (int r = 0; r < 3; ++r) u[r][2] = col[r] / s2;
        } else {
            // sigma3 ~ 0: u3 = u0 x u1 (R is gauge-invariant in this case)
            u[0][2] = u[1][0]*u[2][1] - u[2][0]*u[1][1];
            u[1][2] = u[2][0]*u[0][1] - u[0][0]*u[2][1];
            u[2][2] = u[0][0]*u[1][1] - u[1][0]*u[0][1];
        }
    }

    // d = sign(det(U) * det(V))
    double detU =
        u[0][0]*(u[1][1]*u[2][2] - u[2][1]*u[1][2]) -
        u[0][1]*(u[1][0]*u[2][2] - u[2][0]*u[1][2]) +
        u[0][2]*(u[1][0]*u[2][1] - u[2][0]*u[1][1]);
    double detV =
        v[0][0]*(v[1][1]*v[2][2] - v[2][1]*v[1][2]) -
        v[0][1]*(v[1][0]*v[2][2] - v[2][0]*v[1][2]) +
        v[0][2]*(v[1][0]*v[2][1] - v[2][0]*v[1][1]);
    const double d = (detU * detV >= 0.0) ? 1.0 : -1.0;

    // R = u0 v0^T + u1 v1^T + d * u2 v2^T ; t = tc - R*sc
    double R[3][3];
#pragma unroll
    for (int r = 0; r < 3; ++r)
#pragma unroll
        for (int c = 0; c < 3; ++c)
            R[r][c] = u[r][0]*v[c][0] + u[r][1]*v[c][1] + d * u[r][2]*v[c][2];

    float* Rb = outR + (size_t)b * 9;
#pragma unroll
    for (int r = 0; r < 3; ++r)
#pragma unroll
        for (int c = 0; c < 3; ++c)
            Rb[3*r + c] = (float)R[r][c];

    float* Tb = outT + (size_t)b * 3;
#pragma unroll
    for (int r = 0; r < 3; ++r)
        Tb[r] = (float)(tc[r] - (R[r][0]*sc[0] + R[r][1]*sc[1] + R[r][2]*sc[2]));
}

extern "C" void kernel_launch(void* const* d_in, const int* in_sizes, int n_in,
                              void* d_out, int out_size, void* d_ws, size_t ws_size,
                              hipStream_t stream) {
    const float* src = (const float*)d_in[0];   // (B,N,3)
    const float* tgt = (const float*)d_in[1];   // (B,N,3)
    const float* wts = (const float*)d_in[2];   // (B,1,N)
    float* outR = (float*)d_out;                // (B,3,3) flat
    float* outT = outR + (size_t)B_BATCH * 9;   // (B,3,1) flat
    float* sums = (float*)d_ws;                 // (B,2,16) partial sums

    reduce_kernel<<<B_BATCH * 2, 256, 0, stream>>>(src, tgt, wts, sums);
    svd_kernel<<<B_BATCH / 64, 64, 0, stream>>>(sums, outR, outT);
}